// Round 1
// baseline (238.646 us; speedup 1.0000x reference)
//
#include <hip/hip_runtime.h>

#define Hn 768
#define Bn 16
#define Sn 512
#define En 32
#define Vn 50265

// ---------------- Layer 1: o1 = g1*inst + (1-g1)*sent, g1 = sigmoid(inst@W1_1 + sent@W1_2)
// Only the single event row per batch that the LM head observes is computed.
__global__ __launch_bounds__(256) void gate_layer1(
    const int* __restrict__ batch_arg, const int* __restrict__ event_pos,
    const int* __restrict__ mask_indices, const float* __restrict__ sent_emb,
    const float* __restrict__ emb_table, const float* __restrict__ W1_1,
    const float* __restrict__ W1_2, float* __restrict__ o1_out)
{
    const int b = blockIdx.x;
    const int j = blockIdx.y * 256 + threadIdx.x;

    const int mask = mask_indices[b];
    int estar = -1;
    #pragma unroll
    for (int e = 0; e < En; ++e) {
        if (event_pos[b * En + e] == mask && estar < 0) estar = e;
    }
    const int tok = batch_arg[b * Sn + mask];

    __shared__ float s_inst[Hn];
    __shared__ float s_sent[Hn];
    for (int t = threadIdx.x; t < Hn; t += 256) {
        s_inst[t] = emb_table[(size_t)tok * Hn + t];
        s_sent[t] = (estar >= 0) ? sent_emb[((size_t)b * En + estar) * Hn + t] : 0.f;
    }
    __syncthreads();

    float a = 0.f, c = 0.f;
    #pragma unroll 4
    for (int k = 0; k < Hn; ++k) {
        a = fmaf(s_inst[k], W1_1[k * Hn + j], a);
        c = fmaf(s_sent[k], W1_2[k * Hn + j], c);
    }
    const float g = 1.f / (1.f + expf(-(a + c)));
    o1_out[b * Hn + j] = g * s_inst[j] + (1.f - g) * s_sent[j];
}

// ---------------- Layer 2: o2 = g2*o1 + (1-g2)*typ, written TRANSPOSED as me_t[k][b]
__global__ __launch_bounds__(256) void gate_layer2(
    const int* __restrict__ batch_arg, const int* __restrict__ event_pos,
    const int* __restrict__ mask_indices, const float* __restrict__ type_emb,
    const float* __restrict__ emb_table, const float* __restrict__ W2_1,
    const float* __restrict__ W2_2, const float* __restrict__ o1_in,
    float* __restrict__ me_t)
{
    const int b = blockIdx.x;
    const int j = blockIdx.y * 256 + threadIdx.x;

    const int mask = mask_indices[b];
    int estar = -1;
    #pragma unroll
    for (int e = 0; e < En; ++e) {
        if (event_pos[b * En + e] == mask && estar < 0) estar = e;
    }
    const int tok = batch_arg[b * Sn + mask];

    __shared__ float s_o1[Hn];
    __shared__ float s_typ[Hn];
    for (int t = threadIdx.x; t < Hn; t += 256) {
        s_o1[t]  = o1_in[b * Hn + t];
        s_typ[t] = type_emb[((size_t)b * Sn + mask) * Hn + t];
    }
    __syncthreads();

    float a = 0.f, c = 0.f;
    #pragma unroll 4
    for (int k = 0; k < Hn; ++k) {
        a = fmaf(s_o1[k],  W2_1[k * Hn + j], a);
        c = fmaf(s_typ[k], W2_2[k * Hn + j], c);
    }
    const float g = 1.f / (1.f + expf(-(a + c)));
    float o2 = g * s_o1[j] + (1.f - g) * s_typ[j];
    if (estar < 0) {
        // mask position never updated: raw word embedding flows to the LM head
        o2 = emb_table[(size_t)tok * Hn + j];
    }
    me_t[j * Bn + b] = o2;
}

// ---------------- LM head: out[b][v] = sum_k me_t[k][b] * lm_W[k][v] + lm_b[v]
// Thread-per-v; me_t reads are wave-uniform (scalar-load friendly); lm_W reads coalesced.
__global__ __launch_bounds__(256) void lm_head(
    const float* __restrict__ me_t, const float* __restrict__ lm_W,
    const float* __restrict__ lm_b, float* __restrict__ out)
{
    const int v = blockIdx.x * 256 + threadIdx.x;
    if (v >= Vn) return;

    float acc[Bn];
    #pragma unroll
    for (int b = 0; b < Bn; ++b) acc[b] = 0.f;

    #pragma unroll 8
    for (int k = 0; k < Hn; ++k) {
        const float w = lm_W[(size_t)k * Vn + v];
        const float* __restrict__ m = me_t + k * Bn;
        #pragma unroll
        for (int b = 0; b < Bn; ++b) acc[b] = fmaf(m[b], w, acc[b]);
    }

    const float bias = lm_b[v];
    #pragma unroll
    for (int b = 0; b < Bn; ++b) out[(size_t)b * Vn + v] = acc[b] + bias;
}

extern "C" void kernel_launch(void* const* d_in, const int* in_sizes, int n_in,
                              void* d_out, int out_size, void* d_ws, size_t ws_size,
                              hipStream_t stream) {
    const int*   batch_arg    = (const int*)  d_in[0];
    const int*   event_pos    = (const int*)  d_in[1];
    const int*   mask_indices = (const int*)  d_in[2];
    const float* sent_emb     = (const float*)d_in[3];
    const float* type_emb     = (const float*)d_in[4];
    const float* emb_table    = (const float*)d_in[5];
    const float* W1_1         = (const float*)d_in[6];
    const float* W1_2         = (const float*)d_in[7];
    const float* W2_1         = (const float*)d_in[8];
    const float* W2_2         = (const float*)d_in[9];
    const float* lm_W         = (const float*)d_in[10];
    const float* lm_b         = (const float*)d_in[11];
    float* out = (float*)d_out;

    float* o1_ws = (float*)d_ws;                       // Bn*Hn floats
    float* me_t  = o1_ws + (size_t)Bn * Hn;            // Hn*Bn floats

    dim3 g12(Bn, Hn / 256);
    gate_layer1<<<g12, 256, 0, stream>>>(batch_arg, event_pos, mask_indices,
                                         sent_emb, emb_table, W1_1, W1_2, o1_ws);
    gate_layer2<<<g12, 256, 0, stream>>>(batch_arg, event_pos, mask_indices,
                                         type_emb, emb_table, W2_1, W2_2, o1_ws, me_t);
    lm_head<<<(Vn + 255) / 256, 256, 0, stream>>>(me_t, lm_W, lm_b, out);
}

// Round 2
// 87.574 us; speedup vs baseline: 2.7251x; 2.7251x over previous
//
#include <hip/hip_runtime.h>

#define Hn 768
#define Bn 16
#define Sn 512
#define En 32
#define Vn 50265
#define KS 8
#define KC (Hn / KS)   // 96 k's per split-K chunk

// ---------------- out[b][v] = lm_b[v]  (bias init; split-K kernel accumulates on top)
__global__ __launch_bounds__(256) void out_init(
    const float* __restrict__ lm_b, float* __restrict__ out)
{
    const int v = blockIdx.x * 256 + threadIdx.x;
    if (v < Vn) out[(size_t)blockIdx.y * Vn + v] = lm_b[v];
}

// ---------------- Layer 1: o1 = g1*inst + (1-g1)*sent, g1 = sigmoid(inst@W1_1 + sent@W1_2)
// Only the one event row per batch that the LM head observes is computed.
// Block: 256 threads = 4 waves; wave ks handles k in [ks*192, ks*192+192) for 64 j's.
__global__ __launch_bounds__(256) void gate_layer1(
    const int* __restrict__ batch_arg, const int* __restrict__ event_pos,
    const int* __restrict__ mask_indices, const float* __restrict__ sent_emb,
    const float* __restrict__ emb_table, const float* __restrict__ W1_1,
    const float* __restrict__ W1_2, float* __restrict__ o1_out)
{
    const int b  = blockIdx.x;
    const int j0 = threadIdx.x & 63;
    const int ks = threadIdx.x >> 6;           // wave-uniform
    const int j  = blockIdx.y * 64 + j0;

    const int mask = mask_indices[b];
    int estar = -1;
    #pragma unroll
    for (int e = 0; e < En; ++e)
        if (event_pos[b * En + e] == mask && estar < 0) estar = e;
    const int tok = batch_arg[b * Sn + mask];

    __shared__ float s_inst[Hn];
    __shared__ float s_sent[Hn];
    for (int t = threadIdx.x; t < Hn; t += 256) {
        s_inst[t] = emb_table[(size_t)tok * Hn + t];
        s_sent[t] = (estar >= 0) ? sent_emb[((size_t)b * En + estar) * Hn + t] : 0.f;
    }
    __syncthreads();

    float a = 0.f, c = 0.f;
    const float* __restrict__ w1 = W1_1 + (size_t)ks * 192 * Hn + j;
    const float* __restrict__ w2 = W1_2 + (size_t)ks * 192 * Hn + j;
    const float* __restrict__ si = s_inst + ks * 192;
    const float* __restrict__ ss = s_sent + ks * 192;
    #pragma unroll 8
    for (int k = 0; k < 192; ++k) {
        a = fmaf(si[k], w1[(size_t)k * Hn], a);   // LDS broadcast + coalesced 256B/wave
        c = fmaf(ss[k], w2[(size_t)k * Hn], c);
    }

    __shared__ float r_a[4][64];
    __shared__ float r_c[4][64];
    r_a[ks][j0] = a; r_c[ks][j0] = c;
    __syncthreads();
    if (ks == 0) {
        const float A = r_a[0][j0] + r_a[1][j0] + r_a[2][j0] + r_a[3][j0];
        const float C = r_c[0][j0] + r_c[1][j0] + r_c[2][j0] + r_c[3][j0];
        const float g = 1.f / (1.f + expf(-(A + C)));
        o1_out[b * Hn + j] = g * s_inst[j] + (1.f - g) * s_sent[j];
    }
}

// ---------------- Layer 2: o2 = g2*o1 + (1-g2)*typ, written TRANSPOSED as me_t[k][b]
__global__ __launch_bounds__(256) void gate_layer2(
    const int* __restrict__ batch_arg, const int* __restrict__ event_pos,
    const int* __restrict__ mask_indices, const float* __restrict__ type_emb,
    const float* __restrict__ emb_table, const float* __restrict__ W2_1,
    const float* __restrict__ W2_2, const float* __restrict__ o1_in,
    float* __restrict__ me_t)
{
    const int b  = blockIdx.x;
    const int j0 = threadIdx.x & 63;
    const int ks = threadIdx.x >> 6;
    const int j  = blockIdx.y * 64 + j0;

    const int mask = mask_indices[b];
    int estar = -1;
    #pragma unroll
    for (int e = 0; e < En; ++e)
        if (event_pos[b * En + e] == mask && estar < 0) estar = e;
    const int tok = batch_arg[b * Sn + mask];

    __shared__ float s_o1[Hn];
    __shared__ float s_typ[Hn];
    for (int t = threadIdx.x; t < Hn; t += 256) {
        s_o1[t]  = o1_in[b * Hn + t];
        s_typ[t] = type_emb[((size_t)b * Sn + mask) * Hn + t];
    }
    __syncthreads();

    float a = 0.f, c = 0.f;
    const float* __restrict__ w1 = W2_1 + (size_t)ks * 192 * Hn + j;
    const float* __restrict__ w2 = W2_2 + (size_t)ks * 192 * Hn + j;
    const float* __restrict__ so = s_o1  + ks * 192;
    const float* __restrict__ st = s_typ + ks * 192;
    #pragma unroll 8
    for (int k = 0; k < 192; ++k) {
        a = fmaf(so[k], w1[(size_t)k * Hn], a);
        c = fmaf(st[k], w2[(size_t)k * Hn], c);
    }

    __shared__ float r_a[4][64];
    __shared__ float r_c[4][64];
    r_a[ks][j0] = a; r_c[ks][j0] = c;
    __syncthreads();
    if (ks == 0) {
        const float A = r_a[0][j0] + r_a[1][j0] + r_a[2][j0] + r_a[3][j0];
        const float C = r_c[0][j0] + r_c[1][j0] + r_c[2][j0] + r_c[3][j0];
        const float g = 1.f / (1.f + expf(-(A + C)));
        float o2 = g * s_o1[j] + (1.f - g) * s_typ[j];
        if (estar < 0) o2 = emb_table[(size_t)tok * Hn + j];  // mask row never updated
        me_t[j * Bn + b] = o2;
    }
}

// ---------------- LM head, split-K: out[b][v] += sum_{k in chunk} me_t[k][b]*lm_W[k][v]
__global__ __launch_bounds__(256) void lm_head_splitk(
    const float* __restrict__ me_t, const float* __restrict__ lm_W,
    float* __restrict__ out)
{
    const int kc = blockIdx.y;
    const int v  = blockIdx.x * 256 + threadIdx.x;

    __shared__ float s_m[KC * Bn];     // this chunk's me_t slice (6 KB)
    for (int i = threadIdx.x; i < KC * Bn; i += 256)
        s_m[i] = me_t[kc * KC * Bn + i];
    __syncthreads();
    if (v >= Vn) return;

    float acc[Bn];
    #pragma unroll
    for (int b = 0; b < Bn; ++b) acc[b] = 0.f;

    const float* __restrict__ w = lm_W + (size_t)kc * KC * Vn + v;
    #pragma unroll 8
    for (int k = 0; k < KC; ++k) {
        const float wv = w[(size_t)k * Vn];          // coalesced 256B/wave
        const float* __restrict__ m = s_m + k * Bn;  // LDS broadcast
        #pragma unroll
        for (int b = 0; b < Bn; ++b) acc[b] = fmaf(m[b], wv, acc[b]);
    }

    #pragma unroll
    for (int b = 0; b < Bn; ++b)
        atomicAdd(&out[(size_t)b * Vn + v], acc[b]);
}

extern "C" void kernel_launch(void* const* d_in, const int* in_sizes, int n_in,
                              void* d_out, int out_size, void* d_ws, size_t ws_size,
                              hipStream_t stream) {
    const int*   batch_arg    = (const int*)  d_in[0];
    const int*   event_pos    = (const int*)  d_in[1];
    const int*   mask_indices = (const int*)  d_in[2];
    const float* sent_emb     = (const float*)d_in[3];
    const float* type_emb     = (const float*)d_in[4];
    const float* emb_table    = (const float*)d_in[5];
    const float* W1_1         = (const float*)d_in[6];
    const float* W1_2         = (const float*)d_in[7];
    const float* W2_1         = (const float*)d_in[8];
    const float* W2_2         = (const float*)d_in[9];
    const float* lm_W         = (const float*)d_in[10];
    const float* lm_b         = (const float*)d_in[11];
    float* out = (float*)d_out;

    float* o1_ws = (float*)d_ws;                 // Bn*Hn floats
    float* me_t  = o1_ws + (size_t)Bn * Hn;      // Hn*Bn floats

    dim3 gv((Vn + 255) / 256, Bn);
    out_init<<<gv, 256, 0, stream>>>(lm_b, out);

    dim3 g12(Bn, Hn / 64);
    gate_layer1<<<g12, 256, 0, stream>>>(batch_arg, event_pos, mask_indices,
                                         sent_emb, emb_table, W1_1, W1_2, o1_ws);
    gate_layer2<<<g12, 256, 0, stream>>>(batch_arg, event_pos, mask_indices,
                                         type_emb, emb_table, W2_1, W2_2, o1_ws, me_t);

    dim3 gh((Vn + 255) / 256, KS);
    lm_head_splitk<<<gh, 256, 0, stream>>>(me_t, lm_W, out);
}

// Round 3
// 76.571 us; speedup vs baseline: 3.1167x; 1.1437x over previous
//
#include <hip/hip_runtime.h>

#define Hn 768
#define Bn 16
#define Sn 512
#define En 32
#define Vn 50265

// ---------------- Layer 1: o1 = g1*inst + (1-g1)*sent, g1 = sigmoid(inst@W1_1 + sent@W1_2)
// Only the one event row per batch that the LM head observes is computed.
// Block: 256 threads = 4 waves; wave ks handles k in [ks*192, ks*192+192) for 64 j's.
__global__ __launch_bounds__(256) void gate_layer1(
    const int* __restrict__ batch_arg, const int* __restrict__ event_pos,
    const int* __restrict__ mask_indices, const float* __restrict__ sent_emb,
    const float* __restrict__ emb_table, const float* __restrict__ W1_1,
    const float* __restrict__ W1_2, float* __restrict__ o1_out)
{
    const int b  = blockIdx.x;
    const int j0 = threadIdx.x & 63;
    const int ks = threadIdx.x >> 6;           // wave-uniform
    const int j  = blockIdx.y * 64 + j0;

    const int mask = mask_indices[b];
    int estar = -1;
    #pragma unroll
    for (int e = 0; e < En; ++e)
        if (event_pos[b * En + e] == mask && estar < 0) estar = e;
    const int tok = batch_arg[b * Sn + mask];

    __shared__ float s_inst[Hn];
    __shared__ float s_sent[Hn];
    for (int t = threadIdx.x; t < Hn; t += 256) {
        s_inst[t] = emb_table[(size_t)tok * Hn + t];
        s_sent[t] = (estar >= 0) ? sent_emb[((size_t)b * En + estar) * Hn + t] : 0.f;
    }
    __syncthreads();

    float a = 0.f, c = 0.f;
    const float* __restrict__ w1 = W1_1 + (size_t)ks * 192 * Hn + j;
    const float* __restrict__ w2 = W1_2 + (size_t)ks * 192 * Hn + j;
    const float* __restrict__ si = s_inst + ks * 192;
    const float* __restrict__ ss = s_sent + ks * 192;
    #pragma unroll 8
    for (int k = 0; k < 192; ++k) {
        a = fmaf(si[k], w1[(size_t)k * Hn], a);   // LDS broadcast + coalesced 256B/wave
        c = fmaf(ss[k], w2[(size_t)k * Hn], c);
    }

    __shared__ float r_a[4][64];
    __shared__ float r_c[4][64];
    r_a[ks][j0] = a; r_c[ks][j0] = c;
    __syncthreads();
    if (ks == 0) {
        const float A = r_a[0][j0] + r_a[1][j0] + r_a[2][j0] + r_a[3][j0];
        const float C = r_c[0][j0] + r_c[1][j0] + r_c[2][j0] + r_c[3][j0];
        const float g = 1.f / (1.f + expf(-(A + C)));
        o1_out[b * Hn + j] = g * s_inst[j] + (1.f - g) * s_sent[j];
    }
}

// ---------------- Layer 2: o2 = g2*o1 + (1-g2)*typ, written TRANSPOSED as me_t[k][b]
__global__ __launch_bounds__(256) void gate_layer2(
    const int* __restrict__ batch_arg, const int* __restrict__ event_pos,
    const int* __restrict__ mask_indices, const float* __restrict__ type_emb,
    const float* __restrict__ emb_table, const float* __restrict__ W2_1,
    const float* __restrict__ W2_2, const float* __restrict__ o1_in,
    float* __restrict__ me_t)
{
    const int b  = blockIdx.x;
    const int j0 = threadIdx.x & 63;
    const int ks = threadIdx.x >> 6;
    const int j  = blockIdx.y * 64 + j0;

    const int mask = mask_indices[b];
    int estar = -1;
    #pragma unroll
    for (int e = 0; e < En; ++e)
        if (event_pos[b * En + e] == mask && estar < 0) estar = e;
    const int tok = batch_arg[b * Sn + mask];

    __shared__ float s_o1[Hn];
    __shared__ float s_typ[Hn];
    for (int t = threadIdx.x; t < Hn; t += 256) {
        s_o1[t]  = o1_in[b * Hn + t];
        s_typ[t] = type_emb[((size_t)b * Sn + mask) * Hn + t];
    }
    __syncthreads();

    float a = 0.f, c = 0.f;
    const float* __restrict__ w1 = W2_1 + (size_t)ks * 192 * Hn + j;
    const float* __restrict__ w2 = W2_2 + (size_t)ks * 192 * Hn + j;
    const float* __restrict__ so = s_o1  + ks * 192;
    const float* __restrict__ st = s_typ + ks * 192;
    #pragma unroll 8
    for (int k = 0; k < 192; ++k) {
        a = fmaf(so[k], w1[(size_t)k * Hn], a);
        c = fmaf(st[k], w2[(size_t)k * Hn], c);
    }

    __shared__ float r_a[4][64];
    __shared__ float r_c[4][64];
    r_a[ks][j0] = a; r_c[ks][j0] = c;
    __syncthreads();
    if (ks == 0) {
        const float A = r_a[0][j0] + r_a[1][j0] + r_a[2][j0] + r_a[3][j0];
        const float C = r_c[0][j0] + r_c[1][j0] + r_c[2][j0] + r_c[3][j0];
        const float g = 1.f / (1.f + expf(-(A + C)));
        float o2 = g * s_o1[j] + (1.f - g) * s_typ[j];
        if (estar < 0) o2 = emb_table[(size_t)tok * Hn + j];  // mask row never updated
        me_t[j * Bn + b] = o2;
    }
}

// ---------------- LM head: out[b][v] = sum_k me_t[k][b]*lm_W[k][v] + lm_b[v]
// 786 blocks x 512 threads; 8 waves split K (96 each) for the same 64 v's;
// cross-wave reduce via 32 KB LDS; bias fused. No atomics, no init kernel.
// me_t reads are wave-uniform (readfirstlane'd base) -> SMEM s_load path,
// keeping both the VALU and LDS pipes free for FMAs.
__global__ __launch_bounds__(512, 6) void lm_head(
    const float* __restrict__ me_t, const float* __restrict__ lm_W,
    const float* __restrict__ lm_b, float* __restrict__ out)
{
    const int tid  = threadIdx.x;
    const int lane = tid & 63;
    const int w    = __builtin_amdgcn_readfirstlane(tid >> 6);  // 0..7, SGPR
    const int v    = blockIdx.x * 64 + lane;
    const int vc   = (v < Vn) ? v : 0;           // clamp: garbage lanes never stored

    const int kb = w * 96;
    float acc[Bn];
    #pragma unroll
    for (int b = 0; b < Bn; ++b) acc[b] = 0.f;

    const float* __restrict__ wp = lm_W + (size_t)kb * Vn + vc;
    const float* __restrict__ mp = me_t + kb * Bn;              // uniform base

    #pragma unroll 4
    for (int k = 0; k < 96; ++k) {
        const float wv = wp[(size_t)k * Vn];                    // coalesced 256B/wave
        #pragma unroll
        for (int b = 0; b < Bn; ++b)
            acc[b] = fmaf(mp[k * Bn + b], wv, acc[b]);          // uniform -> s_load
    }

    __shared__ float red[8 * Bn * 64];                          // 32 KB
    #pragma unroll
    for (int b = 0; b < Bn; ++b)
        red[(w * Bn + b) * 64 + lane] = acc[b];
    __syncthreads();

    #pragma unroll
    for (int p0 = 0; p0 < 2; ++p0) {
        const int p  = p0 * 512 + tid;          // 0..1023 = 16 b x 64 v
        const int b  = p >> 6;
        const int l  = p & 63;
        const int vv = blockIdx.x * 64 + l;
        if (vv < Vn) {
            float s = 0.f;
            #pragma unroll
            for (int ww = 0; ww < 8; ++ww) s += red[(ww * Bn + b) * 64 + l];
            out[(size_t)b * Vn + vv] = s + lm_b[vv];
        }
    }
}

extern "C" void kernel_launch(void* const* d_in, const int* in_sizes, int n_in,
                              void* d_out, int out_size, void* d_ws, size_t ws_size,
                              hipStream_t stream) {
    const int*   batch_arg    = (const int*)  d_in[0];
    const int*   event_pos    = (const int*)  d_in[1];
    const int*   mask_indices = (const int*)  d_in[2];
    const float* sent_emb     = (const float*)d_in[3];
    const float* type_emb     = (const float*)d_in[4];
    const float* emb_table    = (const float*)d_in[5];
    const float* W1_1         = (const float*)d_in[6];
    const float* W1_2         = (const float*)d_in[7];
    const float* W2_1         = (const float*)d_in[8];
    const float* W2_2         = (const float*)d_in[9];
    const float* lm_W         = (const float*)d_in[10];
    const float* lm_b         = (const float*)d_in[11];
    float* out = (float*)d_out;

    float* o1_ws = (float*)d_ws;                 // Bn*Hn floats
    float* me_t  = o1_ws + (size_t)Bn * Hn;      // Hn*Bn floats

    dim3 g12(Bn, Hn / 64);
    gate_layer1<<<g12, 256, 0, stream>>>(batch_arg, event_pos, mask_indices,
                                         sent_emb, emb_table, W1_1, W1_2, o1_ws);
    gate_layer2<<<g12, 256, 0, stream>>>(batch_arg, event_pos, mask_indices,
                                         type_emb, emb_table, W2_1, W2_2, o1_ws, me_t);

    lm_head<<<(Vn + 63) / 64, 512, 0, stream>>>(me_t, lm_W, lm_b, out);
}